// Round 7
// baseline (422.170 us; speedup 1.0000x reference)
//
#include <hip/hip_runtime.h>

#define B_ 16
#define T_ 1024
#define S_ 1024
#define D_ 768      // ENC == DEC
#define K3_ 1536    // D_ + D_
#define BS_ (B_ * S_)   // 16384
#define BD_ (B_ * D_)   // 12288
#define NI_ (B_ * T_ * D_)      // 12582912 (inp elems)
#define NW_ (D_ * K3_)          // 1179648  (W elems)
#define NPRE_ 13440             // (NI_+NW_)/4/256 precast blocks
#define ZBASE_ (3072 + NPRE_)   // zero-blocks base

typedef __attribute__((ext_vector_type(8))) _Float16 half8;
typedef __attribute__((ext_vector_type(4))) float float4v;

// ---- fp32 <-> fp16 helpers ----
__device__ __forceinline__ unsigned short f2h(float x) {
    return __builtin_bit_cast(unsigned short, (_Float16)x);
}
__device__ __forceinline__ float h2f(unsigned short u) {
    return (float)__builtin_bit_cast(_Float16, u);
}
__device__ __forceinline__ unsigned pkh2(float a, float b) {
    return (unsigned)f2h(a) | ((unsigned)f2h(b) << 16);
}
__device__ __forceinline__ uint2 pkh4(const float4 v) {
    return make_uint2(pkh2(v.x, v.y), pkh2(v.z, v.w));
}

// ---- async global -> LDS, 16 B per lane (HW scatters to base + lane*16) ----
__device__ __forceinline__ void gl_lds16(const void* g, void* l) {
    __builtin_amdgcn_global_load_lds(
        (const __attribute__((address_space(1))) unsigned int*)g,
        (__attribute__((address_space(3))) unsigned int*)l,
        16, 0, 0);
}

// ===========================================================================
// MFMA GEMM common: 128x128 block, 4 waves (2x2), wave=64x64 of 16x16x32 f16
// LDS: double-buffered linear [2][128][32] halves; 2-phase loop (R4 proven):
//   STAGE(next) -> COMPUTE(cur) -> __syncthreads  (1 barrier per K-step)
// NOTE (R6 post-mortem): linear layout's wave ds_read_b128 is already
// bank-uniform (8 lanes/quad x 8 quads = the 8-cycle floor); no swizzle.
// C/D mapping (verified R1/R2): col = lane&15 (N-op), row = (lane>>4)*4+reg
// ===========================================================================
#define MFMA_PROLOG() \
    const int tid  = threadIdx.x; \
    const int w    = tid >> 6; \
    const int wm   = (w >> 1) * 64; \
    const int wn   = (w & 1) * 64; \
    const int lane = tid & 63; \
    const int q    = lane >> 4; \
    const int lr   = lane & 15; \
    float4v acc[4][4] = {};

// staging: wave w owns rows [w*32, w*32+32); 2 calls of 16 rows per operand.
// lane -> row w*32 + c*16 + (lane>>2), k-chunk (lane&3)*8 halves (16 B).
#define STAGE_PROLOG() \
    const int rl0 = (w << 5) + (lane >> 2); \
    const int cc  = (lane & 3) * 8; \
    const int wb  = w * 1024;

#define MFMA_COMPUTE_F16(AP, BP) \
    { \
        half8 afr[4], bfr[4]; \
        _Pragma("unroll") \
        for (int i = 0; i < 4; i++) \
            afr[i] = *(const half8*)&(AP)[(wm + i * 16 + lr) * 32 + q * 8]; \
        _Pragma("unroll") \
        for (int j = 0; j < 4; j++) \
            bfr[j] = *(const half8*)&(BP)[(wn + j * 16 + lr) * 32 + q * 8]; \
        _Pragma("unroll") \
        for (int i = 0; i < 4; i++) \
            _Pragma("unroll") \
            for (int j = 0; j < 4; j++) \
                acc[i][j] = __builtin_amdgcn_mfma_f32_16x16x32_f16( \
                    afr[i], bfr[j], acc[i][j], 0, 0, 0); \
    }

// ===========================================================================
// prep_all: (a) ctx -> ctxT fp16 [b][d][s] + ctx_h fp16; (b) inp/W -> fp16;
//           (c) zero the colsum accumulator (ws is re-poisoned each run)
// ===========================================================================
__global__ __launch_bounds__(256) void prep_all(
    const float* __restrict__ ctx, const float* __restrict__ inp,
    const float* __restrict__ W,
    unsigned short* __restrict__ ctxT, unsigned short* __restrict__ ctx_h,
    unsigned short* __restrict__ inp_h, unsigned short* __restrict__ W_h,
    float* __restrict__ colsum)
{
    __shared__ unsigned short Ts[64 * 68];
    const int bid = blockIdx.x;
    const int tid = threadIdx.x;
    if (bid < 3072) {               // transpose tiles: 16 s0 x 12 d0 x 16 b
        const int b   = bid / 192;
        const int rem = bid - b * 192;
        const int d0  = (rem >> 4) * 64;
        const int s0  = (rem & 15) * 64;
        const int srel = tid >> 4;              // 0..15
        const int dcol = (tid & 15) * 4;        // 0..60
#pragma unroll
        for (int r = 0; r < 4; r++) {
            const int s = srel + r * 16;
            float4 v = *(const float4*)(ctx + ((size_t)b * S_ + s0 + s) * D_ + d0 + dcol);
            Ts[(dcol + 0) * 68 + s] = f2h(v.x);
            Ts[(dcol + 1) * 68 + s] = f2h(v.y);
            Ts[(dcol + 2) * 68 + s] = f2h(v.z);
            Ts[(dcol + 3) * 68 + s] = f2h(v.w);
            *(uint2*)(ctx_h + ((size_t)b * S_ + s0 + s) * D_ + d0 + dcol) = pkh4(v);
        }
        __syncthreads();
        const int drow = tid >> 2;              // 0..63
        const int scg  = (tid & 3) * 16;        // 0..48
        unsigned short* dst = ctxT + ((size_t)b * D_ + d0 + drow) * S_ + s0 + scg;
#pragma unroll
        for (int p = 0; p < 4; p++) {
            uint2 u = *(const uint2*)&Ts[drow * 68 + scg + p * 4];
            *(uint2*)(dst + p * 4) = u;
        }
    } else if (bid < ZBASE_) {      // fp16 precasts of inp and W
        const size_t i4 = (size_t)(bid - 3072) * 256 + tid;
        const size_t flat = i4 * 4;
        float4 v;
        unsigned short* dst;
        if (flat < NI_) {
            v = ((const float4*)inp)[i4];
            dst = inp_h + flat;
        } else {
            v = *(const float4*)(W + (flat - NI_));
            dst = W_h + (flat - NI_);
        }
        *(uint2*)dst = pkh4(v);
    } else {                        // zero colsum (16 blocks x 256 x float4)
        const int i4 = (bid - ZBASE_) * 256 + tid;
        *(float4*)(colsum + (size_t)i4 * 4) = make_float4(0.f, 0.f, 0.f, 0.f);
    }
}

// ===========================================================================
// GEMM1 (fp16 MFMA, dbuf): scores(fp16) = inputs @ ctx^T -> sc_h [T,B,S]
// A = ctx_h rows (M = s), B = inp_h rows (N = t). XCD-swizzled grid (1024 wg).
// ===========================================================================
__global__ __launch_bounds__(256) void gemm_scores_f16(
    const unsigned short* __restrict__ ctx_h,
    const unsigned short* __restrict__ inp_h,
    unsigned short* __restrict__ sc_h)
{
    // bijective XCD swizzle: 128 consecutive work-ids per XCD (2 batches/XCD)
    const int hwid = blockIdx.x + (blockIdx.y << 3) + (blockIdx.z << 6);
    const int wk   = (hwid & 7) * 128 + (hwid >> 3);
    const int b  = wk >> 6;
    const int t0 = ((wk >> 3) & 7) * 128;
    const int s0 = (wk & 7) * 128;

    __shared__ __align__(16) unsigned short As[2 * 128 * 32];
    __shared__ __align__(16) unsigned short Bs[2 * 128 * 32];

    MFMA_PROLOG();
    STAGE_PROLOG();

    const unsigned short* ga0 = ctx_h + ((size_t)b * S_ + s0 + rl0) * D_ + cc;
    const unsigned short* ga1 = ga0 + (size_t)16 * D_;
    const unsigned short* gb0 = inp_h + ((size_t)b * T_ + t0 + rl0) * D_ + cc;
    const unsigned short* gb1 = gb0 + (size_t)16 * D_;

#define STAGE_G1(bi, kb) \
    { \
        gl_lds16(ga0 + (kb), &As[(bi) * 4096 + wb]); \
        gl_lds16(ga1 + (kb), &As[(bi) * 4096 + wb + 512]); \
        gl_lds16(gb0 + (kb), &Bs[(bi) * 4096 + wb]); \
        gl_lds16(gb1 + (kb), &Bs[(bi) * 4096 + wb + 512]); \
    }

    STAGE_G1(0, 0);
    __syncthreads();
    int cur = 0;
    for (int kb = 32; kb < D_; kb += 32) {
        const int nxt = cur ^ 1;
        STAGE_G1(nxt, kb);
        MFMA_COMPUTE_F16(&As[cur * 4096], &Bs[cur * 4096]);
        __syncthreads();
        cur = nxt;
    }
    MFMA_COMPUTE_F16(&As[cur * 4096], &Bs[cur * 4096]);

#pragma unroll
    for (int i = 0; i < 4; i++)
#pragma unroll
        for (int j = 0; j < 4; j++) {
            const int t = t0 + wn + j * 16 + lr;
            const int s = s0 + wm + i * 16 + q * 4;
            uint2 o;
            o.x = pkh2(acc[i][j][0], acc[i][j][1]);
            o.y = pkh2(acc[i][j][2], acc[i][j][3]);
            *(uint2*)(sc_h + (size_t)t * BS_ + (size_t)b * S_ + s) = o;
        }
}

// ===========================================================================
// softmax_colsum: in-place row softmax on sc (fp16) + atomic column sums.
// grid (B_, T_/8); each block: 8 rows, thread owns 4 s-columns.
// ===========================================================================
__global__ __launch_bounds__(256) void softmax_colsum(
    unsigned short* __restrict__ sc, float* __restrict__ colsum)
{
    const int b  = blockIdx.x;
    const int t0 = blockIdx.y * 8;
    const int tid = threadIdx.x;
    __shared__ float red[8];

    float cs0 = 0.f, cs1 = 0.f, cs2 = 0.f, cs3 = 0.f;
    for (int r = 0; r < 8; r++) {
        unsigned short* row = sc + (size_t)(t0 + r) * BS_ + (size_t)b * S_;
        uint2 u = *(const uint2*)(row + tid * 4);
        float v0 = h2f((unsigned short)(u.x & 0xffff));
        float v1 = h2f((unsigned short)(u.x >> 16));
        float v2 = h2f((unsigned short)(u.y & 0xffff));
        float v3 = h2f((unsigned short)(u.y >> 16));

        float m = fmaxf(fmaxf(v0, v1), fmaxf(v2, v3));
#pragma unroll
        for (int off = 32; off > 0; off >>= 1) m = fmaxf(m, __shfl_xor(m, off));
        if ((tid & 63) == 0) red[tid >> 6] = m;
        __syncthreads();
        m = fmaxf(fmaxf(red[0], red[1]), fmaxf(red[2], red[3]));

        float e0 = __expf(v0 - m), e1 = __expf(v1 - m);
        float e2 = __expf(v2 - m), e3 = __expf(v3 - m);
        float s = (e0 + e1) + (e2 + e3);
#pragma unroll
        for (int off = 32; off > 0; off >>= 1) s += __shfl_xor(s, off);
        if ((tid & 63) == 0) red[4 + (tid >> 6)] = s;
        __syncthreads();
        s = (red[4] + red[5]) + (red[6] + red[7]);

        const float inv = 1.0f / s;
        e0 *= inv; e1 *= inv; e2 *= inv; e3 *= inv;
        uint2 o;
        o.x = pkh2(e0, e1);
        o.y = pkh2(e2, e3);
        *(uint2*)(row + tid * 4) = o;
        cs0 += e0; cs1 += e1; cs2 += e2; cs3 += e3;
        __syncthreads();   // red[] reuse hazard for next row
    }
    float* cp = colsum + (size_t)b * S_ + tid * 4;
    atomicAdd(cp + 0, cs0);
    atomicAdd(cp + 1, cs1);
    atomicAdd(cp + 2, cs2);
    atomicAdd(cp + 3, cs3);
}

// ===========================================================================
// av_out: g = sigmoid(colsum[b][s]) computed inline.
//   out2 (fp32) = av * g / S   (final output 1)
//   av_h (fp16, in place) = f16(av * g)   -> gemm2's B operand
// ===========================================================================
__global__ __launch_bounds__(256) void av_out(
    unsigned short* __restrict__ av_h, const float* __restrict__ colsum,
    float* __restrict__ out2)
{
    const size_t i8 = ((size_t)blockIdx.x * 256 + threadIdx.x) * 8;
    const int s = (int)(i8 & (S_ - 1));
    const int b = (int)((i8 >> 10) & (B_ - 1));
    const uint4 u = *(const uint4*)(av_h + i8);
    const float4 c0 = *(const float4*)(colsum + b * S_ + s);
    const float4 c1 = *(const float4*)(colsum + b * S_ + s + 4);
    const float g0 = 1.0f / (1.0f + __expf(-c0.x));
    const float g1 = 1.0f / (1.0f + __expf(-c0.y));
    const float g2 = 1.0f / (1.0f + __expf(-c0.z));
    const float g3 = 1.0f / (1.0f + __expf(-c0.w));
    const float g4 = 1.0f / (1.0f + __expf(-c1.x));
    const float g5 = 1.0f / (1.0f + __expf(-c1.y));
    const float g6 = 1.0f / (1.0f + __expf(-c1.z));
    const float g7 = 1.0f / (1.0f + __expf(-c1.w));
    float a0 = h2f((unsigned short)(u.x & 0xffff)) * g0;
    float a1 = h2f((unsigned short)(u.x >> 16))    * g1;
    float a2 = h2f((unsigned short)(u.y & 0xffff)) * g2;
    float a3 = h2f((unsigned short)(u.y >> 16))    * g3;
    float a4 = h2f((unsigned short)(u.z & 0xffff)) * g4;
    float a5 = h2f((unsigned short)(u.z >> 16))    * g5;
    float a6 = h2f((unsigned short)(u.w & 0xffff)) * g6;
    float a7 = h2f((unsigned short)(u.w >> 16))    * g7;
    const float is = 1.0f / (float)S_;
    *(float4*)(out2 + i8)     = make_float4(a0 * is, a1 * is, a2 * is, a3 * is);
    *(float4*)(out2 + i8 + 4) = make_float4(a4 * is, a5 * is, a6 * is, a7 * is);
    uint4 o;
    o.x = pkh2(a0, a1); o.y = pkh2(a2, a3);
    o.z = pkh2(a4, a5); o.w = pkh2(a6, a7);
    *(uint4*)(av_h + i8) = o;
}

// ===========================================================================
// GEMM2 (fp16, dbuf): c_h[b,t,d] = f16( (av_g' @ ctxT) * ws/S + bs )
// A = ctxT rows (M = d), B = av_h rows (= av*gate, N = t). XCD swizzle (768).
// ===========================================================================
__global__ __launch_bounds__(256) void gemm_ctx_f16(
    const unsigned short* __restrict__ ctxT, const unsigned short* __restrict__ av_h,
    const float* __restrict__ w_scale, const float* __restrict__ b_scale,
    unsigned short* __restrict__ c_h)
{
    const int hwid = blockIdx.x + blockIdx.y * 8 + blockIdx.z * 48;
    const int wk   = (hwid & 7) * 96 + (hwid >> 3);
    const int t0 = (wk % 8) * 128;
    const int d0 = ((wk / 8) % 6) * 128;
    const int b  = wk / 48;

    __shared__ __align__(16) unsigned short As[2 * 128 * 32];
    __shared__ __align__(16) unsigned short Bs[2 * 128 * 32];

    MFMA_PROLOG();
    STAGE_PROLOG();

    const unsigned short* ga0 = ctxT + ((size_t)b * D_ + d0 + rl0) * S_ + cc;
    const unsigned short* ga1 = ga0 + (size_t)16 * S_;
    const unsigned short* gb0 = av_h + (size_t)(t0 + rl0) * BS_ + (size_t)b * S_ + cc;
    const unsigned short* gb1 = gb0 + (size_t)16 * BS_;

#define STAGE_G2(bi, sbk) \
    { \
        gl_lds16(ga0 + (sbk), &As[(bi) * 4096 + wb]); \
        gl_lds16(ga1 + (sbk), &As[(bi) * 4096 + wb + 512]); \
        gl_lds16(gb0 + (sbk), &Bs[(bi) * 4096 + wb]); \
        gl_lds16(gb1 + (sbk), &Bs[(bi) * 4096 + wb + 512]); \
    }

    STAGE_G2(0, 0);
    __syncthreads();
    int cur = 0;
    for (int sb = 32; sb < S_; sb += 32) {
        const int nxt = cur ^ 1;
        STAGE_G2(nxt, sb);
        MFMA_COMPUTE_F16(&As[cur * 4096], &Bs[cur * 4096]);
        __syncthreads();
        cur = nxt;
    }
    MFMA_COMPUTE_F16(&As[cur * 4096], &Bs[cur * 4096]);

    const float wsc = w_scale[0] * (1.0f / (float)S_);
    const float bsc = b_scale[0];
#pragma unroll
    for (int i = 0; i < 4; i++)
#pragma unroll
        for (int j = 0; j < 4; j++) {
            const int d = d0 + wm + i * 16 + q * 4;
            const int t = t0 + wn + j * 16 + lr;
            uint2 o;
            o.x = pkh2(acc[i][j][0] * wsc + bsc, acc[i][j][1] * wsc + bsc);
            o.y = pkh2(acc[i][j][2] * wsc + bsc, acc[i][j][3] * wsc + bsc);
            *(uint2*)(c_h + ((size_t)b * T_ + t) * D_ + d) = o;
        }
}

// ===========================================================================
// GEMM3 (fp16, dbuf): h = prelu(concat(c_h, inp_h) @ W_h^T + bias) -> out0
// A = W_h rows (M = d), B = concat rows (N = n). grid (6, 128), XCD swizzle.
// ===========================================================================
__global__ __launch_bounds__(256) void gemm_out_f16(
    const unsigned short* __restrict__ c_h, const unsigned short* __restrict__ inp_h,
    const unsigned short* __restrict__ W_h, const float* __restrict__ bias,
    const float* __restrict__ prelu_a, float* __restrict__ out0)
{
    const int hwid = blockIdx.x + blockIdx.y * 6;
    const int wk   = (hwid & 7) * 96 + (hwid >> 3);
    const int d0 = (wk % 6) * 128;
    const int n0 = (wk / 6) * 128;

    __shared__ __align__(16) unsigned short As[2 * 128 * 32];
    __shared__ __align__(16) unsigned short Bs[2 * 128 * 32];

    MFMA_PROLOG();
    STAGE_PROLOG();

    const unsigned short* ga0  = W_h + (size_t)(d0 + rl0) * K3_ + cc;
    const unsigned short* ga1  = ga0 + (size_t)16 * K3_;
    const unsigned short* gbc0 = c_h + (size_t)(n0 + rl0) * D_ + cc;
    const unsigned short* gbi0 = inp_h + (size_t)(n0 + rl0) * D_ + cc;

#define STAGE_G3(bi, kb) \
    { \
        const unsigned short* gbx = ((kb) < D_) ? gbc0 + (kb) : gbi0 + ((kb) - D_); \
        gl_lds16(ga0 + (kb), &As[(bi) * 4096 + wb]); \
        gl_lds16(ga1 + (kb), &As[(bi) * 4096 + wb + 512]); \
        gl_lds16(gbx, &Bs[(bi) * 4096 + wb]); \
        gl_lds16(gbx + (size_t)16 * D_, &Bs[(bi) * 4096 + wb + 512]); \
    }

    STAGE_G3(0, 0);
    __syncthreads();
    int cur = 0;
    for (int kb = 32; kb < K3_; kb += 32) {
        const int nxt = cur ^ 1;
        STAGE_G3(nxt, kb);
        MFMA_COMPUTE_F16(&As[cur * 4096], &Bs[cur * 4096]);
        __syncthreads();
        cur = nxt;
    }
    MFMA_COMPUTE_F16(&As[cur * 4096], &Bs[cur * 4096]);

    const float pa = prelu_a[0];
#pragma unroll
    for (int i = 0; i < 4; i++) {
        const int d = d0 + wm + i * 16 + q * 4;
        const float4 bz = *(const float4*)(bias + d);
#pragma unroll
        for (int j = 0; j < 4; j++) {
            const int n = n0 + wn + j * 16 + lr;
            const int bb = n >> 10;
            const int t = n & (T_ - 1);
            float4 h;
            h.x = acc[i][j][0] + bz.x;
            h.y = acc[i][j][1] + bz.y;
            h.z = acc[i][j][2] + bz.z;
            h.w = acc[i][j][3] + bz.w;
            h.x = h.x >= 0.0f ? h.x : pa * h.x;
            h.y = h.y >= 0.0f ? h.y : pa * h.y;
            h.z = h.z >= 0.0f ? h.z : pa * h.z;
            h.w = h.w >= 0.0f ? h.w : pa * h.w;
            *(float4*)(out0 + (size_t)t * BD_ + (size_t)bb * D_ + d) = h;
        }
    }
}

// ===========================================================================
extern "C" void kernel_launch(void* const* d_in, const int* in_sizes, int n_in,
                              void* d_out, int out_size, void* d_ws, size_t ws_size,
                              hipStream_t stream)
{
    const float* inputs  = (const float*)d_in[0];   // [B,T,768]
    const float* context = (const float*)d_in[1];   // [B,S,768]
    const float* W_out   = (const float*)d_in[2];   // [768,1536]
    const float* b_out   = (const float*)d_in[3];   // [768]
    const float* w_scale = (const float*)d_in[4];
    const float* b_scale = (const float*)d_in[5];
    const float* prelu_a = (const float*)d_in[6];

    float* out0 = (float*)d_out;                          // [T,B,768]
    float* out2 = out0 + (size_t)T_ * B_ * D_;            // [T,B,S] (av_g)

    // ws layout (fp16 regions then fp32 regions):
    unsigned short* c_h   = (unsigned short*)d_ws;                 // B*T*D
    unsigned short* ctxT  = c_h   + (size_t)B_ * T_ * D_;          // B*D*S
    unsigned short* av_h  = ctxT  + (size_t)B_ * D_ * S_;          // T*B*S (scores->av)
    unsigned short* inp_h = av_h  + (size_t)T_ * B_ * S_;          // B*T*D
    unsigned short* W_h   = inp_h + (size_t)B_ * T_ * D_;          // D*K3
    float* colsum  = (float*)(W_h + (size_t)NW_);                  // B*S

    // 0. precasts + transpose + colsum zero (ctx_h staged in c_h region;
    //    lifetimes disjoint: gemm2 writes c_h only after gemm1 consumed ctx_h)
    prep_all<<<ZBASE_ + 16, 256, 0, stream>>>(
        context, inputs, W_out, ctxT, c_h, inp_h, W_h, colsum);
    // 1. scores (fp16) -> av_h buffer (fp16 MFMA, dbuf, XCD swizzle)
    gemm_scores_f16<<<dim3(S_ / 128, T_ / 128, B_), 256, 0, stream>>>(
        c_h /*ctx_h*/, inp_h, av_h);
    // 2. softmax in place + atomic column sums (fused)
    softmax_colsum<<<dim3(B_, T_ / 8), 256, 0, stream>>>(av_h, colsum);
    // 3. out2 = av*sigmoid(colsum)/S (output 1); av_h *= gate in place
    av_out<<<(int)(((size_t)T_ * B_ * S_ / 8) / 256), 256, 0, stream>>>(
        av_h, colsum, out2);
    // 4. c_h = f16((av_g' @ ctxT) * ws/S + bs)   [fp16 MFMA, dbuf]
    gemm_ctx_f16<<<dim3(T_ / 128, D_ / 128, B_), 256, 0, stream>>>(
        ctxT, av_h, w_scale, b_scale, c_h);
    // 5. h = prelu(concat @ W^T + b) -> out0   [fp16 MFMA, dbuf]
    gemm_out_f16<<<dim3(D_ / 128, (B_ * T_) / 128), 256, 0, stream>>>(
        c_h, inp_h, W_h, b_out, prelu_a, out0);
}

// Round 8
// 390.269 us; speedup vs baseline: 1.0817x; 1.0817x over previous
//
#include <hip/hip_runtime.h>

#define B_ 16
#define T_ 1024
#define S_ 1024
#define D_ 768      // ENC == DEC
#define K3_ 1536    // D_ + D_
#define BS_ (B_ * S_)   // 16384
#define BD_ (B_ * D_)   // 12288
#define NI_ (B_ * T_ * D_)      // 12582912 (inp elems)
#define NW_ (D_ * K3_)          // 1179648  (W elems)
#define NPRE_ 13440             // (NI_+NW_)/4/256 precast blocks

typedef __attribute__((ext_vector_type(8))) _Float16 half8;
typedef __attribute__((ext_vector_type(4))) float float4v;

// ---- fp32 <-> fp16 helpers ----
__device__ __forceinline__ unsigned short f2h(float x) {
    return __builtin_bit_cast(unsigned short, (_Float16)x);
}
__device__ __forceinline__ float h2f(unsigned short u) {
    return (float)__builtin_bit_cast(_Float16, u);
}
__device__ __forceinline__ unsigned pkh2(float a, float b) {
    return (unsigned)f2h(a) | ((unsigned)f2h(b) << 16);
}
__device__ __forceinline__ uint2 pkh4(const float4 v) {
    return make_uint2(pkh2(v.x, v.y), pkh2(v.z, v.w));
}

// ---- async global -> LDS, 16 B per lane (HW scatters to base + lane*16) ----
__device__ __forceinline__ void gl_lds16(const void* g, void* l) {
    __builtin_amdgcn_global_load_lds(
        (const __attribute__((address_space(1))) unsigned int*)g,
        (__attribute__((address_space(3))) unsigned int*)l,
        16, 0, 0);
}

// ===========================================================================
// MFMA GEMM common (R4-proven): 128x128 block, 4 waves (2x2), 16x16x32 f16
// LDS: double-buffered linear [2][128][32] halves; 2-phase loop:
//   STAGE(next) -> COMPUTE(cur) -> __syncthreads  (1 barrier per K-step)
// Linear layout is bank-uniform for the wave's ds_read_b128 (8 lanes/quad x
// 8 quads = the 8-cycle floor) — no swizzle (R6 post-mortem).
// C/D mapping (verified R1/R2): col = lane&15 (N-op), row = (lane>>4)*4+reg
// ===========================================================================
#define MFMA_PROLOG() \
    const int tid  = threadIdx.x; \
    const int w    = tid >> 6; \
    const int wm   = (w >> 1) * 64; \
    const int wn   = (w & 1) * 64; \
    const int lane = tid & 63; \
    const int q    = lane >> 4; \
    const int lr   = lane & 15; \
    float4v acc[4][4] = {};

// staging: wave w owns rows [w*32, w*32+32); 2 calls of 16 rows per operand.
#define STAGE_PROLOG() \
    const int rl0 = (w << 5) + (lane >> 2); \
    const int cc  = (lane & 3) * 8; \
    const int wb  = w * 1024;

#define MFMA_COMPUTE_F16(AP, BP) \
    { \
        half8 afr[4], bfr[4]; \
        _Pragma("unroll") \
        for (int i = 0; i < 4; i++) \
            afr[i] = *(const half8*)&(AP)[(wm + i * 16 + lr) * 32 + q * 8]; \
        _Pragma("unroll") \
        for (int j = 0; j < 4; j++) \
            bfr[j] = *(const half8*)&(BP)[(wn + j * 16 + lr) * 32 + q * 8]; \
        _Pragma("unroll") \
        for (int i = 0; i < 4; i++) \
            _Pragma("unroll") \
            for (int j = 0; j < 4; j++) \
                acc[i][j] = __builtin_amdgcn_mfma_f32_16x16x32_f16( \
                    afr[i], bfr[j], acc[i][j], 0, 0, 0); \
    }

// ===========================================================================
// prep_all: (a) ctx -> ctxT fp16 [b][d][s] + ctx_h fp16; (b) inp/W -> fp16
// ===========================================================================
__global__ __launch_bounds__(256) void prep_all(
    const float* __restrict__ ctx, const float* __restrict__ inp,
    const float* __restrict__ W,
    unsigned short* __restrict__ ctxT, unsigned short* __restrict__ ctx_h,
    unsigned short* __restrict__ inp_h, unsigned short* __restrict__ W_h)
{
    __shared__ unsigned short Ts[64 * 68];
    const int bid = blockIdx.x;
    const int tid = threadIdx.x;
    if (bid < 3072) {               // transpose tiles: 16 s0 x 12 d0 x 16 b
        const int b   = bid / 192;
        const int rem = bid - b * 192;
        const int d0  = (rem >> 4) * 64;
        const int s0  = (rem & 15) * 64;
        const int srel = tid >> 4;              // 0..15
        const int dcol = (tid & 15) * 4;        // 0..60
#pragma unroll
        for (int r = 0; r < 4; r++) {
            const int s = srel + r * 16;
            float4 v = *(const float4*)(ctx + ((size_t)b * S_ + s0 + s) * D_ + d0 + dcol);
            Ts[(dcol + 0) * 68 + s] = f2h(v.x);
            Ts[(dcol + 1) * 68 + s] = f2h(v.y);
            Ts[(dcol + 2) * 68 + s] = f2h(v.z);
            Ts[(dcol + 3) * 68 + s] = f2h(v.w);
            *(uint2*)(ctx_h + ((size_t)b * S_ + s0 + s) * D_ + d0 + dcol) = pkh4(v);
        }
        __syncthreads();
        const int drow = tid >> 2;              // 0..63
        const int scg  = (tid & 3) * 16;        // 0..48
        unsigned short* dst = ctxT + ((size_t)b * D_ + d0 + drow) * S_ + s0 + scg;
#pragma unroll
        for (int p = 0; p < 4; p++) {
            uint2 u = *(const uint2*)&Ts[drow * 68 + scg + p * 4];
            *(uint2*)(dst + p * 4) = u;
        }
    } else {                        // fp16 precasts of inp and W
        const size_t i4 = (size_t)(bid - 3072) * 256 + tid;
        const size_t flat = i4 * 4;
        float4 v;
        unsigned short* dst;
        if (flat < NI_) {
            v = ((const float4*)inp)[i4];
            dst = inp_h + flat;
        } else {
            v = *(const float4*)(W + (flat - NI_));
            dst = W_h + (flat - NI_);
        }
        *(uint2*)dst = pkh4(v);
    }
}

// ===========================================================================
// GEMM1 (fp16 MFMA, dbuf): scores(fp16) = inputs @ ctx^T -> sc_h [T,B,S]
// A = ctx_h rows (M = s), B = inp_h rows (N = t). XCD-swizzled grid (1024 wg).
// ===========================================================================
__global__ __launch_bounds__(256) void gemm_scores_f16(
    const unsigned short* __restrict__ ctx_h,
    const unsigned short* __restrict__ inp_h,
    unsigned short* __restrict__ sc_h)
{
    // bijective XCD swizzle: 128 consecutive work-ids per XCD (2 batches/XCD)
    const int hwid = blockIdx.x + (blockIdx.y << 3) + (blockIdx.z << 6);
    const int wk   = (hwid & 7) * 128 + (hwid >> 3);
    const int b  = wk >> 6;
    const int t0 = ((wk >> 3) & 7) * 128;
    const int s0 = (wk & 7) * 128;

    __shared__ __align__(16) unsigned short As[2 * 128 * 32];
    __shared__ __align__(16) unsigned short Bs[2 * 128 * 32];

    MFMA_PROLOG();
    STAGE_PROLOG();

    const unsigned short* ga0 = ctx_h + ((size_t)b * S_ + s0 + rl0) * D_ + cc;
    const unsigned short* ga1 = ga0 + (size_t)16 * D_;
    const unsigned short* gb0 = inp_h + ((size_t)b * T_ + t0 + rl0) * D_ + cc;
    const unsigned short* gb1 = gb0 + (size_t)16 * D_;

#define STAGE_G1(bi, kb) \
    { \
        gl_lds16(ga0 + (kb), &As[(bi) * 4096 + wb]); \
        gl_lds16(ga1 + (kb), &As[(bi) * 4096 + wb + 512]); \
        gl_lds16(gb0 + (kb), &Bs[(bi) * 4096 + wb]); \
        gl_lds16(gb1 + (kb), &Bs[(bi) * 4096 + wb + 512]); \
    }

    STAGE_G1(0, 0);
    __syncthreads();
    int cur = 0;
    for (int kb = 32; kb < D_; kb += 32) {
        const int nxt = cur ^ 1;
        STAGE_G1(nxt, kb);
        MFMA_COMPUTE_F16(&As[cur * 4096], &Bs[cur * 4096]);
        __syncthreads();
        cur = nxt;
    }
    MFMA_COMPUTE_F16(&As[cur * 4096], &Bs[cur * 4096]);

#pragma unroll
    for (int i = 0; i < 4; i++)
#pragma unroll
        for (int j = 0; j < 4; j++) {
            const int t = t0 + wn + j * 16 + lr;
            const int s = s0 + wm + i * 16 + q * 4;
            uint2 o;
            o.x = pkh2(acc[i][j][0], acc[i][j][1]);
            o.y = pkh2(acc[i][j][2], acc[i][j][3]);
            *(uint2*)(sc_h + (size_t)t * BS_ + (size_t)b * S_ + s) = o;
        }
}

// ===========================================================================
// softmax_rows: sc (fp16 scores) -> av fp16, in place. One row per block.
// ===========================================================================
__global__ __launch_bounds__(256) void softmax_rows(
    unsigned short* __restrict__ sc)
{
    const int bid = blockIdx.x;
    const int b = bid & (B_ - 1);
    const int t = bid / B_;
    unsigned short* row = sc + (size_t)t * BS_ + (size_t)b * S_;
    const int tid = threadIdx.x;

    uint2 u = *(const uint2*)(row + tid * 4);
    float v0 = h2f((unsigned short)(u.x & 0xffff)), v1 = h2f((unsigned short)(u.x >> 16));
    float v2 = h2f((unsigned short)(u.y & 0xffff)), v3 = h2f((unsigned short)(u.y >> 16));
    float m = fmaxf(fmaxf(v0, v1), fmaxf(v2, v3));
#pragma unroll
    for (int off = 32; off > 0; off >>= 1) m = fmaxf(m, __shfl_xor(m, off));

    __shared__ float red[8];
    if ((tid & 63) == 0) red[tid >> 6] = m;
    __syncthreads();
    m = fmaxf(fmaxf(red[0], red[1]), fmaxf(red[2], red[3]));

    float e0 = __expf(v0 - m), e1 = __expf(v1 - m);
    float e2 = __expf(v2 - m), e3 = __expf(v3 - m);
    float s = (e0 + e1) + (e2 + e3);
#pragma unroll
    for (int off = 32; off > 0; off >>= 1) s += __shfl_xor(s, off);
    if ((tid & 63) == 0) red[4 + (tid >> 6)] = s;
    __syncthreads();
    s = (red[4] + red[5]) + (red[6] + red[7]);

    const float inv = 1.0f / s;
    uint2 o;
    o.x = pkh2(e0 * inv, e1 * inv);
    o.y = pkh2(e2 * inv, e3 * inv);
    *(uint2*)(row + tid * 4) = o;
}

// ===========================================================================
// colsum_part: partial[c][b][s] = sum over t-chunk c (128 rows) of av_h
// grid (S/512, B, T/128), 256 threads, 2 s per thread. Non-atomic.
// ===========================================================================
__global__ __launch_bounds__(256) void colsum_part(
    const unsigned short* __restrict__ av_h, float* __restrict__ partial)
{
    const int b = blockIdx.y;
    const int c = blockIdx.z;
    const int s2 = blockIdx.x * 512 + threadIdx.x * 2;
    const unsigned short* p = av_h + (size_t)(c * 128) * BS_ + (size_t)b * S_ + s2;
    float s0 = 0.0f, s1 = 0.0f;
#pragma unroll 8
    for (int t = 0; t < 128; t++) {
        const unsigned u = *(const unsigned*)(p + (size_t)t * BS_);
        s0 += h2f((unsigned short)(u & 0xffff));
        s1 += h2f((unsigned short)(u >> 16));
    }
    *(float2*)(partial + ((size_t)c * B_ + b) * S_ + s2) = make_float2(s0, s1);
}

// ===========================================================================
// av_out: colsum = sum_c partial (L2-resident, 512 KB); g = sigmoid(colsum);
//   out2 (fp32) = av * g / S   (final output 1)
//   av_h (fp16, in place) = f16(av * g)   -> gemm2's B operand
// ===========================================================================
__global__ __launch_bounds__(256) void av_out(
    unsigned short* __restrict__ av_h, const float* __restrict__ partial,
    float* __restrict__ out2)
{
    const size_t i8 = ((size_t)blockIdx.x * 256 + threadIdx.x) * 8;
    const int s = (int)(i8 & (S_ - 1));
    const int b = (int)((i8 >> 10) & (B_ - 1));
    float4 c0 = make_float4(0.f, 0.f, 0.f, 0.f);
    float4 c1 = make_float4(0.f, 0.f, 0.f, 0.f);
#pragma unroll
    for (int c = 0; c < T_ / 128; c++) {
        const float* pp = partial + ((size_t)c * B_ + b) * S_ + s;
        const float4 p0 = *(const float4*)(pp);
        const float4 p1 = *(const float4*)(pp + 4);
        c0.x += p0.x; c0.y += p0.y; c0.z += p0.z; c0.w += p0.w;
        c1.x += p1.x; c1.y += p1.y; c1.z += p1.z; c1.w += p1.w;
    }
    const float g0 = 1.0f / (1.0f + __expf(-c0.x));
    const float g1 = 1.0f / (1.0f + __expf(-c0.y));
    const float g2 = 1.0f / (1.0f + __expf(-c0.z));
    const float g3 = 1.0f / (1.0f + __expf(-c0.w));
    const float g4 = 1.0f / (1.0f + __expf(-c1.x));
    const float g5 = 1.0f / (1.0f + __expf(-c1.y));
    const float g6 = 1.0f / (1.0f + __expf(-c1.z));
    const float g7 = 1.0f / (1.0f + __expf(-c1.w));
    const uint4 u = *(const uint4*)(av_h + i8);
    float a0 = h2f((unsigned short)(u.x & 0xffff)) * g0;
    float a1 = h2f((unsigned short)(u.x >> 16))    * g1;
    float a2 = h2f((unsigned short)(u.y & 0xffff)) * g2;
    float a3 = h2f((unsigned short)(u.y >> 16))    * g3;
    float a4 = h2f((unsigned short)(u.z & 0xffff)) * g4;
    float a5 = h2f((unsigned short)(u.z >> 16))    * g5;
    float a6 = h2f((unsigned short)(u.w & 0xffff)) * g6;
    float a7 = h2f((unsigned short)(u.w >> 16))    * g7;
    const float is = 1.0f / (float)S_;
    *(float4*)(out2 + i8)     = make_float4(a0 * is, a1 * is, a2 * is, a3 * is);
    *(float4*)(out2 + i8 + 4) = make_float4(a4 * is, a5 * is, a6 * is, a7 * is);
    uint4 o;
    o.x = pkh2(a0, a1); o.y = pkh2(a2, a3);
    o.z = pkh2(a4, a5); o.w = pkh2(a6, a7);
    *(uint4*)(av_h + i8) = o;
}

// ===========================================================================
// GEMM2 (fp16, dbuf): c_h[b,t,d] = f16( (av_g' @ ctxT) * ws/S + bs )
// A = ctxT rows (M = d), B = av_h rows (= av*gate, N = t). XCD swizzle (768).
// ===========================================================================
__global__ __launch_bounds__(256) void gemm_ctx_f16(
    const unsigned short* __restrict__ ctxT, const unsigned short* __restrict__ av_h,
    const float* __restrict__ w_scale, const float* __restrict__ b_scale,
    unsigned short* __restrict__ c_h)
{
    const int hwid = blockIdx.x + blockIdx.y * 8 + blockIdx.z * 48;
    const int wk   = (hwid & 7) * 96 + (hwid >> 3);
    const int t0 = (wk % 8) * 128;
    const int d0 = ((wk / 8) % 6) * 128;
    const int b  = wk / 48;

    __shared__ __align__(16) unsigned short As[2 * 128 * 32];
    __shared__ __align__(16) unsigned short Bs[2 * 128 * 32];

    MFMA_PROLOG();
    STAGE_PROLOG();

    const unsigned short* ga0 = ctxT + ((size_t)b * D_ + d0 + rl0) * S_ + cc;
    const unsigned short* ga1 = ga0 + (size_t)16 * S_;
    const unsigned short* gb0 = av_h + (size_t)(t0 + rl0) * BS_ + (size_t)b * S_ + cc;
    const unsigned short* gb1 = gb0 + (size_t)16 * BS_;

#define STAGE_G2(bi, sbk) \
    { \
        gl_lds16(ga0 + (sbk), &As[(bi) * 4096 + wb]); \
        gl_lds16(ga1 + (sbk), &As[(bi) * 4096 + wb + 512]); \
        gl_lds16(gb0 + (sbk), &Bs[(bi) * 4096 + wb]); \
        gl_lds16(gb1 + (sbk), &Bs[(bi) * 4096 + wb + 512]); \
    }

    STAGE_G2(0, 0);
    __syncthreads();
    int cur = 0;
    for (int sb = 32; sb < S_; sb += 32) {
        const int nxt = cur ^ 1;
        STAGE_G2(nxt, sb);
        MFMA_COMPUTE_F16(&As[cur * 4096], &Bs[cur * 4096]);
        __syncthreads();
        cur = nxt;
    }
    MFMA_COMPUTE_F16(&As[cur * 4096], &Bs[cur * 4096]);

    const float wsc = w_scale[0] * (1.0f / (float)S_);
    const float bsc = b_scale[0];
#pragma unroll
    for (int i = 0; i < 4; i++)
#pragma unroll
        for (int j = 0; j < 4; j++) {
            const int d = d0 + wm + i * 16 + q * 4;
            const int t = t0 + wn + j * 16 + lr;
            uint2 o;
            o.x = pkh2(acc[i][j][0] * wsc + bsc, acc[i][j][1] * wsc + bsc);
            o.y = pkh2(acc[i][j][2] * wsc + bsc, acc[i][j][3] * wsc + bsc);
            *(uint2*)(c_h + ((size_t)b * T_ + t) * D_ + d) = o;
        }
}

// ===========================================================================
// GEMM3 (fp16, dbuf): h = prelu(concat(c_h, inp_h) @ W_h^T + bias) -> out0
// A = W_h rows (M = d), B = concat rows (N = n). grid (6, 128), XCD swizzle.
// ===========================================================================
__global__ __launch_bounds__(256) void gemm_out_f16(
    const unsigned short* __restrict__ c_h, const unsigned short* __restrict__ inp_h,
    const unsigned short* __restrict__ W_h, const float* __restrict__ bias,
    const float* __restrict__ prelu_a, float* __restrict__ out0)
{
    const int hwid = blockIdx.x + blockIdx.y * 6;
    const int wk   = (hwid & 7) * 96 + (hwid >> 3);
    const int d0 = (wk % 6) * 128;
    const int n0 = (wk / 6) * 128;

    __shared__ __align__(16) unsigned short As[2 * 128 * 32];
    __shared__ __align__(16) unsigned short Bs[2 * 128 * 32];

    MFMA_PROLOG();
    STAGE_PROLOG();

    const unsigned short* ga0  = W_h + (size_t)(d0 + rl0) * K3_ + cc;
    const unsigned short* ga1  = ga0 + (size_t)16 * K3_;
    const unsigned short* gbc0 = c_h + (size_t)(n0 + rl0) * D_ + cc;
    const unsigned short* gbi0 = inp_h + (size_t)(n0 + rl0) * D_ + cc;

#define STAGE_G3(bi, kb) \
    { \
        const unsigned short* gbx = ((kb) < D_) ? gbc0 + (kb) : gbi0 + ((kb) - D_); \
        gl_lds16(ga0 + (kb), &As[(bi) * 4096 + wb]); \
        gl_lds16(ga1 + (kb), &As[(bi) * 4096 + wb + 512]); \
        gl_lds16(gbx, &Bs[(bi) * 4096 + wb]); \
        gl_lds16(gbx + (size_t)16 * D_, &Bs[(bi) * 4096 + wb + 512]); \
    }

    STAGE_G3(0, 0);
    __syncthreads();
    int cur = 0;
    for (int kb = 32; kb < K3_; kb += 32) {
        const int nxt = cur ^ 1;
        STAGE_G3(nxt, kb);
        MFMA_COMPUTE_F16(&As[cur * 4096], &Bs[cur * 4096]);
        __syncthreads();
        cur = nxt;
    }
    MFMA_COMPUTE_F16(&As[cur * 4096], &Bs[cur * 4096]);

    const float pa = prelu_a[0];
#pragma unroll
    for (int i = 0; i < 4; i++) {
        const int d = d0 + wm + i * 16 + q * 4;
        const float4 bz = *(const float4*)(bias + d);
#pragma unroll
        for (int j = 0; j < 4; j++) {
            const int n = n0 + wn + j * 16 + lr;
            const int bb = n >> 10;
            const int t = n & (T_ - 1);
            float4 h;
            h.x = acc[i][j][0] + bz.x;
            h.y = acc[i][j][1] + bz.y;
            h.z = acc[i][j][2] + bz.z;
            h.w = acc[i][j][3] + bz.w;
            h.x = h.x >= 0.0f ? h.x : pa * h.x;
            h.y = h.y >= 0.0f ? h.y : pa * h.y;
            h.z = h.z >= 0.0f ? h.z : pa * h.z;
            h.w = h.w >= 0.0f ? h.w : pa * h.w;
            *(float4*)(out0 + (size_t)t * BD_ + (size_t)bb * D_ + d) = h;
        }
    }
}

// ===========================================================================
extern "C" void kernel_launch(void* const* d_in, const int* in_sizes, int n_in,
                              void* d_out, int out_size, void* d_ws, size_t ws_size,
                              hipStream_t stream)
{
    const float* inputs  = (const float*)d_in[0];   // [B,T,768]
    const float* context = (const float*)d_in[1];   // [B,S,768]
    const float* W_out   = (const float*)d_in[2];   // [768,1536]
    const float* b_out   = (const float*)d_in[3];   // [768]
    const float* w_scale = (const float*)d_in[4];
    const float* b_scale = (const float*)d_in[5];
    const float* prelu_a = (const float*)d_in[6];

    float* out0 = (float*)d_out;                          // [T,B,768]
    float* out2 = out0 + (size_t)T_ * B_ * D_;            // [T,B,S] (av_g)

    // ws layout (fp16 regions then fp32 regions):
    unsigned short* c_h   = (unsigned short*)d_ws;                 // B*T*D
    unsigned short* ctxT  = c_h   + (size_t)B_ * T_ * D_;          // B*D*S
    unsigned short* av_h  = ctxT  + (size_t)B_ * D_ * S_;          // T*B*S (scores->av)
    unsigned short* inp_h = av_h  + (size_t)T_ * B_ * S_;          // B*T*D
    unsigned short* W_h   = inp_h + (size_t)B_ * T_ * D_;          // D*K3
    float* partial = (float*)(W_h + (size_t)NW_);                  // 8*B*S

    // 0. precasts + transpose (ctx_h staged in c_h region; lifetimes disjoint:
    //    gemm2 writes c_h only after gemm1 consumed ctx_h)
    prep_all<<<3072 + NPRE_, 256, 0, stream>>>(
        context, inputs, W_out, ctxT, c_h, inp_h, W_h);
    // 1. scores (fp16) -> av_h buffer (fp16 MFMA, dbuf, XCD swizzle)
    gemm_scores_f16<<<dim3(S_ / 128, T_ / 128, B_), 256, 0, stream>>>(
        c_h /*ctx_h*/, inp_h, av_h);
    // 2. softmax in place (one row per block, 16384 blocks)
    softmax_rows<<<B_ * T_, 256, 0, stream>>>(av_h);
    // 3. column partial sums over t (non-atomic)
    colsum_part<<<dim3(S_ / 512, B_, T_ / 128), 256, 0, stream>>>(av_h, partial);
    // 4. out2 = av*sigmoid(colsum)/S (output 1); av_h *= gate in place
    av_out<<<(int)(((size_t)T_ * B_ * S_ / 8) / 256), 256, 0, stream>>>(
        av_h, partial, out2);
    // 5. c_h = f16((av_g' @ ctxT) * ws/S + bs)   [fp16 MFMA, dbuf]
    gemm_ctx_f16<<<dim3(T_ / 128, D_ / 128, B_), 256, 0, stream>>>(
        ctxT, av_h, w_scale, b_scale, c_h);
    // 6. h = prelu(concat @ W^T + b) -> out0   [fp16 MFMA, dbuf]
    gemm_out_f16<<<dim3(D_ / 128, (B_ * T_) / 128), 256, 0, stream>>>(
        c_h, inp_h, W_h, b_out, prelu_a, out0);
}